// Round 6
// baseline (230.598 us; speedup 1.0000x reference)
//
#include <hip/hip_runtime.h>
#include <stdint.h>

#define BATCH   65536
#define BM      128
#define NSTEP   16

typedef __bf16 bf16x8 __attribute__((ext_vector_type(8)));
typedef float  f32x16 __attribute__((ext_vector_type(16)));

__device__ __forceinline__ uint32_t f2bf1(float v) {
  uint32_t u = __float_as_uint(v);
  return (u + 0x7FFFu + ((u >> 16) & 1u)) >> 16;   // RNE bf16
}

__device__ __forceinline__ float fast_sigmoid(float x) {
  return __builtin_amdgcn_rcpf(1.0f + __expf(-x));
}
__device__ __forceinline__ float fast_tanh(float x) {
  return 1.0f - 2.0f * __builtin_amdgcn_rcpf(1.0f + __expf(2.0f * x));
}

// ---------------- prep: weights -> bf16 fragment image (r4 layout, verified) ----------------
// 16B chunk t = nb*8192 + ks*512 + kc*128 + g*32 + u5
// holds Wcat[k = ks*32 + kc*8 + i][col = g*256 + nb*32 + u5], i = 0..7
// Wcat rows 0..255 = kernel (x), 256..511 = recurrent_kernel (h).
__global__ __launch_bounds__(256) void prep_weights(
    const float* __restrict__ wk, const float* __restrict__ wr,
    uint4* __restrict__ img) {
  int t  = blockIdx.x * 256 + threadIdx.x;   // 0..65535
  int u5 = t & 31;
  int g  = (t >> 5) & 3;
  int kc = (t >> 7) & 3;
  int ks = (t >> 9) & 15;
  int nb = t >> 13;
  int k0  = ks * 32 + kc * 8;
  int col = g * 256 + nb * 32 + u5;
  uint32_t o[4];
#pragma unroll
  for (int p = 0; p < 4; ++p) {
    int k = k0 + p * 2;
    float s0 = (k     < 256) ? wk[(size_t)k * 1024 + col]       : wr[(size_t)(k - 256) * 1024 + col];
    float s1 = (k + 1 < 256) ? wk[(size_t)(k + 1) * 1024 + col] : wr[(size_t)(k - 255) * 1024 + col];
    o[p] = f2bf1(s0) | (f2bf1(s1) << 16);
  }
  img[t] = make_uint4(o[0], o[1], o[2], o[3]);
}

// ---------------- fused LSTM GEMM: all-register, zero LDS, zero barriers ----------------
// block: 128 rows x (4 gates x 32 units), 4 waves M-stacked (wave = 32x128).
// Waves are fully independent: latency hidden by per-wave 3-deep A / 2-deep B
// register pipelines + ~24 outstanding loads; no cross-wave coupling at all.
// __launch_bounds__(256,2): unlock the VGPR budget r2 was denied (it got 64 and spilled).
__global__ __launch_bounds__(256, 2) void lstm_fused(
    const float* __restrict__ xp, const float* __restrict__ hp,
    const float* __restrict__ cp, const float* __restrict__ bp,
    const uint4* __restrict__ img, float* __restrict__ outp) {

  const int tid  = threadIdx.x;
  const int lane = tid & 63;
  const int wv   = tid >> 6;
  const int ln31 = lane & 31;
  const int hi32 = lane >> 5;

  // XCD-chunked bijective swizzle (4096 % 8 == 0): 8 nb-sharers of one A panel on one XCD.
  const int orig = blockIdx.x;
  const int wg   = (orig & 7) * 512 + (orig >> 3);
  const int nb   = wg & 7;
  const int rt   = wg >> 3;

  const int row = rt * BM + wv * 32 + ln31;
  const float* ar = xp + (size_t)row * 256;
  const float* hr = hp + (size_t)row * 256;
  const int koff = hi32 * 8;

  // per-lane B base: chunk = nb*8192 + ks*512 + hi32*128 + hh*256 + g*32 + ln31
  const uint4* bsrc = img + (size_t)nb * 8192 + hi32 * 128 + ln31;

  f32x16 acc[4];
#pragma unroll
  for (int g = 0; g < 4; ++g)
#pragma unroll
    for (int i = 0; i < 16; ++i) acc[g][i] = 0.0f;

  float4 a[3][4];   // 3-deep A pipeline (fp32), static idx via full unroll
  uint4  b[2][8];   // 2-deep B pipeline (bf16 frags)

  auto loadA = [&](int ks, float4* A) {
    const float* s = ((ks < 8) ? ar : hr) + (ks & 7) * 32 + koff;
    A[0] = *(const float4*)(s);
    A[1] = *(const float4*)(s + 4);
    A[2] = *(const float4*)(s + 16);
    A[3] = *(const float4*)(s + 20);
  };
  auto loadB = [&](int ks, uint4* B) {
    const uint4* s = bsrc + (size_t)ks * 512;
#pragma unroll
    for (int hh = 0; hh < 2; ++hh)
#pragma unroll
      for (int g = 0; g < 4; ++g)
        B[hh * 4 + g] = s[hh * 256 + g * 32];
  };
  auto mkfrag = [&](const float4* A, bf16x8* F) {
#pragma unroll
    for (int h = 0; h < 2; ++h) {
      float4 lo = A[h * 2], hi = A[h * 2 + 1];
      bf16x8 f;
      f[0] = (__bf16)lo.x; f[1] = (__bf16)lo.y; f[2] = (__bf16)lo.z; f[3] = (__bf16)lo.w;
      f[4] = (__bf16)hi.x; f[5] = (__bf16)hi.y; f[6] = (__bf16)hi.z; f[7] = (__bf16)hi.w;
      F[h] = f;
    }
  };

  // prologue: fill pipelines (A 3-deep, B 2-deep) -> 20 loads in flight
  loadA(0, a[0]);
  loadB(0, b[0]);
  loadA(1, a[1]);
  loadB(1, b[1]);
  loadA(2, a[2]);

#pragma unroll
  for (int ks = 0; ks < NSTEP; ++ks) {
    bf16x8 F[2];
    mkfrag(a[ks % 3], F);
    if (ks + 3 < NSTEP) loadA(ks + 3, a[ks % 3]);   // WAR: issues after mkfrag consumed slot
    __builtin_amdgcn_s_setprio(1);
#pragma unroll
    for (int hh = 0; hh < 2; ++hh)
#pragma unroll
      for (int g = 0; g < 4; ++g) {
        bf16x8 bfr = __builtin_bit_cast(bf16x8, b[ks & 1][hh * 4 + g]);
        acc[g] = __builtin_amdgcn_mfma_f32_32x32x16_bf16(F[hh], bfr, acc[g], 0, 0, 0);
      }
    __builtin_amdgcn_s_setprio(0);
    if (ks + 2 < NSTEP) loadB(ks + 2, b[ks & 1]);   // WAR: issues after MFMAs read slot
  }

  // ---- epilogue: gates + cell update; c loaded NT here (frees prologue regs) ----
  const int u = nb * 32 + ln31;
  const float bi  = bp[u];
  const float bf_ = bp[256 + u];
  const float bg  = bp[512 + u];
  const float bo  = bp[768 + u];
  const int rowbase = rt * BM + wv * 32 + 4 * hi32;
  float* outh = outp;
  float* outc = outp + (size_t)BATCH * 256;
#pragma unroll
  for (int r = 0; r < 16; ++r) {
    int orow = rowbase + (r & 3) + 8 * (r >> 2);
    size_t idx = (size_t)orow * 256 + u;
    float zi = acc[0][r] + bi;
    float zf = acc[1][r] + bf_;
    float zg = acc[2][r] + bg;
    float zo = acc[3][r] + bo;
    float iv = fast_sigmoid(zi);
    float fv = fast_sigmoid(zf);
    float gv = fast_tanh(zg);
    float ov = fast_sigmoid(zo);
    float cv = __builtin_nontemporal_load(cp + idx);
    float cn = fv * cv + iv * gv;
    float hn = ov * fast_tanh(cn);
    __builtin_nontemporal_store(hn, outh + idx);
    __builtin_nontemporal_store(cn, outc + idx);
  }
}

extern "C" void kernel_launch(void* const* d_in, const int* in_sizes, int n_in,
                              void* d_out, int out_size, void* d_ws, size_t ws_size,
                              hipStream_t stream) {
  const float* x  = (const float*)d_in[0];
  const float* h  = (const float*)d_in[1];
  const float* c  = (const float*)d_in[2];
  const float* wk = (const float*)d_in[3];
  const float* wr = (const float*)d_in[4];
  const float* b  = (const float*)d_in[5];
  prep_weights<<<256, 256, 0, stream>>>(wk, wr, (uint4*)d_ws);   // 1 MB bf16 image
  lstm_fused<<<4096, 256, 0, stream>>>(x, h, c, b,
                                       (const uint4*)d_ws, (float*)d_out);
}

// Round 7
// 208.943 us; speedup vs baseline: 1.1036x; 1.1036x over previous
//
#include <hip/hip_runtime.h>
#include <stdint.h>

#define BATCH   65536
#define BM      128
#define NSTEP   16

typedef __bf16 bf16x8 __attribute__((ext_vector_type(8)));
typedef float  f32x16 __attribute__((ext_vector_type(16)));

__device__ __forceinline__ uint32_t f2bf1(float v) {
  uint32_t u = __float_as_uint(v);
  return (u + 0x7FFFu + ((u >> 16) & 1u)) >> 16;   // RNE bf16
}

__device__ __forceinline__ float fast_sigmoid(float x) {
  return __builtin_amdgcn_rcpf(1.0f + __expf(-x));
}
__device__ __forceinline__ float fast_tanh(float x) {
  return 1.0f - 2.0f * __builtin_amdgcn_rcpf(1.0f + __expf(2.0f * x));
}

// pinned async VMEM: issue order fixed by volatile, dest regs forced live
#define GLB4(dst, ptr, OFF) \
  asm volatile("global_load_dwordx4 %0, %1, off offset:" #OFF \
               : "=v"(dst) : "v"(ptr))
#define WAITVM(N) \
  do { asm volatile("s_waitcnt vmcnt(" #N ")" ::: "memory"); \
       __builtin_amdgcn_sched_barrier(0); } while (0)

// ---------------- prep: weights -> bf16 fragment image (r4 layout, proven) ----------------
// 16B chunk t = nb*8192 + ks*512 + kc*128 + g*32 + u5
// holds Wcat[k = ks*32 + kc*8 + i][col = g*256 + nb*32 + u5], i = 0..7
// Wcat rows 0..255 = kernel (x), 256..511 = recurrent_kernel (h).
__global__ __launch_bounds__(256) void prep_weights(
    const float* __restrict__ wk, const float* __restrict__ wr,
    uint4* __restrict__ img) {
  int t  = blockIdx.x * 256 + threadIdx.x;   // 0..65535
  int u5 = t & 31;
  int g  = (t >> 5) & 3;
  int kc = (t >> 7) & 3;
  int ks = (t >> 9) & 15;
  int nb = t >> 13;
  int k0  = ks * 32 + kc * 8;
  int col = g * 256 + nb * 32 + u5;
  uint32_t o[4];
#pragma unroll
  for (int p = 0; p < 4; ++p) {
    int k = k0 + p * 2;
    float s0 = (k     < 256) ? wk[(size_t)k * 1024 + col]       : wr[(size_t)(k - 256) * 1024 + col];
    float s1 = (k + 1 < 256) ? wk[(size_t)(k + 1) * 1024 + col] : wr[(size_t)(k - 255) * 1024 + col];
    o[p] = f2bf1(s0) | (f2bf1(s1) << 16);
  }
  img[t] = make_uint4(o[0], o[1], o[2], o[3]);
}

// ---------------- fused LSTM GEMM: asm-pinned register pipeline, no LDS, no barriers ----------------
// block: 128 rows x (4 gates x 32 units), 4 independent M-stacked waves (wave = 32x128).
// B 3-deep / A 2-deep asm register pipelines; steady-state s_waitcnt vmcnt(20).
__global__ __launch_bounds__(256, 2) void lstm_fused(
    const float* __restrict__ xp, const float* __restrict__ hp,
    const float* __restrict__ cp, const float* __restrict__ bp,
    const uint4* __restrict__ img, float* __restrict__ outp) {

  const int tid  = threadIdx.x;
  const int lane = tid & 63;
  const int wv   = tid >> 6;
  const int ln31 = lane & 31;
  const int hi32 = lane >> 5;

  // XCD-chunked bijective swizzle (4096 % 8 == 0): 8 nb-sharers of one A panel on one XCD.
  const int orig = blockIdx.x;
  const int wg   = (orig & 7) * 512 + (orig >> 3);
  const int nb   = wg & 7;
  const int rt   = wg >> 3;

  const int row = rt * BM + wv * 32 + ln31;
  const int koff = hi32 * 8;
  const char* pa = (const char*)(xp + (size_t)row * 256 + koff);  // A ptr, +128B/step
  const char* hb = (const char*)(hp + (size_t)row * 256 + koff);  // switch at ks==8
  // B ptrs: +8192B/step; pb1 = pb0 + 4096 (hh=1 half)
  const char* pb0 = (const char*)(img + (size_t)nb * 8192 + hi32 * 128 + ln31);
  const char* pb1 = pb0 + 4096;

  f32x16 acc[4];
#pragma unroll
  for (int g = 0; g < 4; ++g)
#pragma unroll
    for (int i = 0; i < 16; ++i) acc[g][i] = 0.0f;

  float4 a[2][4];   // A fp32, 2-slot rotation
  uint4  b[3][8];   // B frags, 3-slot rotation (16 iters unrolled -> i%3 static)

#define ISSUE_A(slot)                         \
  do { GLB4(a[slot][0], pa, 0);               \
       GLB4(a[slot][1], pa, 16);              \
       GLB4(a[slot][2], pa, 64);              \
       GLB4(a[slot][3], pa, 80);              \
       pa += 128; } while (0)
#define ISSUE_B(slot)                         \
  do { GLB4(b[slot][0], pb0, 0);              \
       GLB4(b[slot][1], pb0, 512);            \
       GLB4(b[slot][2], pb0, 1024);           \
       GLB4(b[slot][3], pb0, 1536);           \
       GLB4(b[slot][4], pb1, 0);              \
       GLB4(b[slot][5], pb1, 512);            \
       GLB4(b[slot][6], pb1, 1024);           \
       GLB4(b[slot][7], pb1, 1536);           \
       pb0 += 8192; pb1 += 8192; } while (0)

  // prologue: B0 A0 B1 A1 B2  (A(k) older than B(k+1) -> vmcnt(20) retires A(i),B(i) exactly)
  ISSUE_B(0);
  ISSUE_A(0);
  ISSUE_B(1);
  ISSUE_A(1);
  ISSUE_B(2);

#pragma unroll
  for (int i = 0; i < NSTEP; ++i) {
    if (i < 14)      WAITVM(20);   // keep B(i+1),A(i+1),B(i+2) in flight; A(i),B(i) retired
    else if (i == 14) WAITVM(12);
    else              WAITVM(0);

    // fp32 -> bf16 fragments (compiler emits cvt_pk pairs)
    bf16x8 F[2];
#pragma unroll
    for (int h = 0; h < 2; ++h) {
      float4 lo = a[i & 1][h * 2], hi = a[i & 1][h * 2 + 1];
      bf16x8 f;
      f[0] = (__bf16)lo.x; f[1] = (__bf16)lo.y; f[2] = (__bf16)lo.z; f[3] = (__bf16)lo.w;
      f[4] = (__bf16)hi.x; f[5] = (__bf16)hi.y; f[6] = (__bf16)hi.z; f[7] = (__bf16)hi.w;
      F[h] = f;
    }

    __builtin_amdgcn_s_setprio(1);
#pragma unroll
    for (int h = 0; h < 2; ++h)
#pragma unroll
      for (int g = 0; g < 4; ++g) {
        bf16x8 bfr = __builtin_bit_cast(bf16x8, b[i % 3][h * 4 + g]);
        acc[g] = __builtin_amdgcn_mfma_f32_32x32x16_bf16(F[h], bfr, acc[g], 0, 0, 0);
      }
    __builtin_amdgcn_s_setprio(0);

    // reissue freed slots (A first, then B -> keeps the vmcnt arithmetic exact)
    if (i + 2 < NSTEP) {
      if (i + 2 == 8) pa = hb;      // static branch: switch x -> h panel
      ISSUE_A((i & 1));
    }
    if (i + 3 < NSTEP) ISSUE_B(((i + 3) % 3));
  }

  // ---- epilogue: all asm VMEM retired (vmcnt(0) at i=15); compiler manages c/bias waits ----
  const int u = nb * 32 + ln31;
  const float bi  = bp[u];
  const float bf_ = bp[256 + u];
  const float bg  = bp[512 + u];
  const float bo  = bp[768 + u];
  const int rowbase = rt * BM + wv * 32 + 4 * hi32;
  float* outh = outp;
  float* outc = outp + (size_t)BATCH * 256;
#pragma unroll
  for (int r = 0; r < 16; ++r) {
    int orow = rowbase + (r & 3) + 8 * (r >> 2);
    size_t idx = (size_t)orow * 256 + u;
    float zi = acc[0][r] + bi;
    float zf = acc[1][r] + bf_;
    float zg = acc[2][r] + bg;
    float zo = acc[3][r] + bo;
    float iv = fast_sigmoid(zi);
    float fv = fast_sigmoid(zf);
    float gv = fast_tanh(zg);
    float ov = fast_sigmoid(zo);
    float cv = __builtin_nontemporal_load(cp + idx);
    float cn = fv * cv + iv * gv;
    float hn = ov * fast_tanh(cn);
    __builtin_nontemporal_store(hn, outh + idx);
    __builtin_nontemporal_store(cn, outc + idx);
  }
}

extern "C" void kernel_launch(void* const* d_in, const int* in_sizes, int n_in,
                              void* d_out, int out_size, void* d_ws, size_t ws_size,
                              hipStream_t stream) {
  const float* x  = (const float*)d_in[0];
  const float* h  = (const float*)d_in[1];
  const float* c  = (const float*)d_in[2];
  const float* wk = (const float*)d_in[3];
  const float* wr = (const float*)d_in[4];
  const float* b  = (const float*)d_in[5];
  prep_weights<<<256, 256, 0, stream>>>(wk, wr, (uint4*)d_ws);   // 1 MB bf16 image
  lstm_fused<<<4096, 256, 0, stream>>>(x, h, c, b,
                                       (const uint4*)d_ws, (float*)d_out);
}